// Round 17
// baseline (461.154 us; speedup 1.0000x reference)
//
#include <hip/hip_runtime.h>
#include <stdint.h>

// Group / KNN: B=16, N=16384, NUM_GROUP=512, GROUP_SIZE=32.
// d_out = neighborhood [16][512][32][3] ++ center [16][512][3] ++ ids [16][512]
//
// r17 = r16's grid algorithm (verified correct: same absmax canary as the
// brute-force line) with k_query rebuilt wave-cooperatively:
//  - cube/shell enumerated as contiguous x-row SPANS (cells contiguous in
//    index -> point ranges contiguous in `sorted`)
//  - 64-lane batches per span, ballot-compaction instead of LDS atomics
//    (r16: per-point atomicAdd on ONE LDS address = full serialization,
//    2.1M bank conflicts, 400 us)
//  - phase 1 stores only dd bits (u32, cap 2048; register stale-count
//    fallback beyond cap) for the certificate; phase 2 re-scans the
//    certified cube collecting keys dd < dmin^2 into a UNIONED buffer
//  - exact (dd,idx) counting-sort ranking; exact wave fallback otherwise.

#define NPTS  16384
#define NBAT  16
#define NGRP  512
#define GSZ   32
#define GDIM  32
#define NCELL (GDIM * GDIM * GDIM)
#define GLO   (-4.0f)
#define GINV  (4.0f)
#define GH    (0.25f)
#define QW    2        // waves per k_query block
#define DDCAP 2048     // phase-1 dd storage (u32), unioned with SELCAP u64
#define SELCAP 1024    // phase-2 key storage (u64)

__device__ __forceinline__ int cell_of(float x) {
    int c = (int)floorf((x - GLO) * GINV);
    return c < 0 ? 0 : (c > GDIM - 1 ? GDIM - 1 : c);
}

// ---- K1: per-cell counts -------------------------------------------------
__global__ __launch_bounds__(256) void k_count(const float* __restrict__ xyz,
                                               unsigned* __restrict__ counts) {
    const int i = blockIdx.x * 256 + threadIdx.x;
    const int b = i >> 14;
    const float* p = xyz + (size_t)i * 3;
    const int cx = cell_of(p[0]), cy = cell_of(p[1]), cz = cell_of(p[2]);
    atomicAdd(&counts[b * NCELL + (cz * GDIM + cy) * GDIM + cx], 1u);
}

// ---- K2: per-batch exclusive scan (one 1024-thread block per batch) ------
__global__ __launch_bounds__(1024) void k_scan(const unsigned* __restrict__ counts,
                                               unsigned* __restrict__ offs,
                                               unsigned* __restrict__ work) {
    const int b = blockIdx.x;
    const int t = threadIdx.x;
    const int lane = t & 63, w = t >> 6;
    const unsigned* c = counts + (size_t)b * NCELL;
    unsigned loc[32];
    unsigned sum = 0;
#pragma unroll
    for (int j = 0; j < 32; ++j) { loc[j] = c[t * 32 + j]; sum += loc[j]; }
    unsigned v = sum;
#pragma unroll
    for (int d = 1; d < 64; d <<= 1) {
        const unsigned o = __shfl_up(v, d, 64);
        if (lane >= d) v += o;
    }
    __shared__ unsigned s_ws[16];
    if (lane == 63) s_ws[w] = v;
    __syncthreads();
    unsigned wbase = 0;
    for (int j = 0; j < w; ++j) wbase += s_ws[j];
    unsigned run = wbase + v - sum;
    unsigned* ob = offs + (size_t)b * NCELL;
    unsigned* wb = work + (size_t)b * NCELL;
#pragma unroll
    for (int j = 0; j < 32; ++j) {
        ob[t * 32 + j] = run;
        wb[t * 32 + j] = run;
        run += loc[j];
    }
}

// ---- K3: scatter points into cell-sorted float4 {x,y,z,idx} --------------
__global__ __launch_bounds__(256) void k_scatter(const float* __restrict__ xyz,
                                                 unsigned* __restrict__ work,
                                                 float4* __restrict__ sorted) {
    const int i = blockIdx.x * 256 + threadIdx.x;
    const int b = i >> 14, n = i & (NPTS - 1);
    const float* p = xyz + (size_t)i * 3;
    const float x = p[0], y = p[1], z = p[2];
    const int cx = cell_of(x), cy = cell_of(y), cz = cell_of(z);
    const unsigned pos = atomicAdd(&work[b * NCELL + (cz * GDIM + cy) * GDIM + cx], 1u);
    sorted[(size_t)b * NPTS + pos] = make_float4(x, y, z, (float)n);
}

// ---- K4: query — one wave per group, ballot-compacted spans --------------
__global__ __launch_bounds__(QW * 64) void k_query(
    const float* __restrict__ xyz,
    const unsigned* __restrict__ offs,
    const float4* __restrict__ sorted,
    float* __restrict__ out_nb,
    float* __restrict__ out_ctr,
    float* __restrict__ out_ids)
{
    const int wl   = threadIdx.x >> 6;
    const int lane = threadIdx.x & 63;
    const int wid  = blockIdx.x * QW + wl;            // 0 .. 8191
    const int b    = wid >> 9;
    const int g    = wid & 511;
    const int nc   = g * 32;

    const float* base = xyz + (size_t)b * NPTS * 3;
    const float c0 = base[nc * 3 + 0];
    const float c1 = base[nc * 3 + 1];
    const float c2 = base[nc * 3 + 2];

    __shared__ unsigned long long s_buf[QW][SELCAP];  // 8 KB/wave (union)
    __shared__ unsigned s_win[QW][GSZ];
    unsigned* ddbuf = (unsigned*)(&s_buf[wl][0]);     // u32[DDCAP]
    unsigned long long* selbuf = &s_buf[wl][0];       // u64[SELCAP]

    const int ci = cell_of(c0), cj = cell_of(c1), ck = cell_of(c2);
    const unsigned* boffs = offs + (size_t)b * NCELL;
    const float4*   bsrt  = sorted + (size_t)b * NPTS;
    const unsigned long long lmask = (1ull << lane) - 1ull;

    int cnt = 0, selcnt = 0, cs = 0;
    unsigned dmbits = 0, dm2bits = 0;
    int s_cert = -1;

    auto span = [&](int cz, int cy, int x0, int x1, bool collect) {
        const int cell0 = (cz * GDIM + cy) * GDIM + x0;
        const int cell1 = cell0 + (x1 - x0);
        const unsigned st = boffs[cell0];
        const unsigned en = (cell1 == NCELL - 1) ? (unsigned)NPTS : boffs[cell1 + 1];
        for (unsigned pb = st; pb < en; pb += 64) {
            const unsigned p = pb + lane;
            const bool valid = p < en;
            float4 pt = make_float4(0.f, 0.f, 0.f, 0.f);
            if (valid) pt = bsrt[p];
            const float d0 = pt.x - c0, d1 = pt.y - c1, d2v = pt.z - c2;
            const float dd = __builtin_fmaf(d2v, d2v,
                             __builtin_fmaf(d1, d1, d0 * d0));
            const unsigned db = __float_as_uint(dd);
            if (!collect) {
                const unsigned long long mask = __ballot(valid);
                const int pos = cnt + (int)__popcll(mask & lmask);
                if (valid && pos < DDCAP) ddbuf[pos] = db;
                cnt += (int)__popcll(mask);
                cs += (valid && db < dmbits) ? 1 : 0;
            } else {
                const bool sel = valid && db < dm2bits;
                const unsigned long long mask = __ballot(sel);
                const int pos = selcnt + (int)__popcll(mask & lmask);
                if (sel && pos < SELCAP)
                    selbuf[pos] = ((unsigned long long)db << 32)
                                  | (unsigned)(int)pt.w;
                selcnt += (int)__popcll(mask);
            }
        }
    };

    auto do_shell = [&](int s, bool collect) {
        if (s == 0) { span(ck, cj, ci, ci, collect); return; }
        const int zlo = ck - s, zhi = ck + s;
        const int ylo = cj - s, yhi = cj + s;
        const int xlo = ci - s < 0 ? 0 : ci - s;
        const int xhi = ci + s > GDIM - 1 ? GDIM - 1 : ci + s;
        const int yloc = ylo < 0 ? 0 : ylo;
        const int yhic = yhi > GDIM - 1 ? GDIM - 1 : yhi;
        if (zlo >= 0)   for (int cy = yloc; cy <= yhic; ++cy) span(zlo, cy, xlo, xhi, collect);
        if (zhi < GDIM) for (int cy = yloc; cy <= yhic; ++cy) span(zhi, cy, xlo, xhi, collect);
        const int zl2 = (zlo + 1) < 0 ? 0 : zlo + 1;
        const int zh2 = (zhi - 1) > GDIM - 1 ? GDIM - 1 : zhi - 1;
        if (ylo >= 0)   for (int cz = zl2; cz <= zh2; ++cz) span(cz, ylo, xlo, xhi, collect);
        if (yhi < GDIM) for (int cz = zl2; cz <= zh2; ++cz) span(cz, yhi, xlo, xhi, collect);
        const int yl2 = (ylo + 1) < 0 ? 0 : ylo + 1;
        const int yh2 = (yhi - 1) > GDIM - 1 ? GDIM - 1 : yhi - 1;
        const bool xl = (ci - s) >= 0, xh = (ci + s) < GDIM;
        if (xl || xh)
            for (int cz = zl2; cz <= zh2; ++cz)
                for (int cy = yl2; cy <= yh2; ++cy) {
                    if (xl) span(cz, cy, ci - s, ci - s, collect);
                    if (xh) span(cz, cy, ci + s, ci + s, collect);
                }
    };

    // ---- Phase 1: expand shells until certificate -----------------------
    for (int s = 0; s < GDIM && s_cert < 0; ++s) {
        float dmin = 1e30f;
        if (ci - s > 0)        dmin = fminf(dmin, c0 - (GLO + (ci - s) * GH));
        if (ci + s < GDIM - 1) dmin = fminf(dmin, (GLO + (ci + s + 1) * GH) - c0);
        if (cj - s > 0)        dmin = fminf(dmin, c1 - (GLO + (cj - s) * GH));
        if (cj + s < GDIM - 1) dmin = fminf(dmin, (GLO + (cj + s + 1) * GH) - c1);
        if (ck - s > 0)        dmin = fminf(dmin, c2 - (GLO + (ck - s) * GH));
        if (ck + s < GDIM - 1) dmin = fminf(dmin, (GLO + (ck + s + 1) * GH) - c2);
        dmbits = __float_as_uint(dmin * dmin);        // inf if all clamped
        do_shell(s, false);
        if (cnt >= GSZ) {
            int tot = 0;
            if (cnt <= DDCAP) {
                for (int j = lane; j < cnt; j += 64)
                    tot += (ddbuf[j] < dmbits) ? 1 : 0;
            } else {
                tot = cs;                              // conservative (stale)
            }
#pragma unroll
            for (int m = 32; m >= 1; m >>= 1) tot += __shfl_xor(tot, m, 64);
            if (tot >= GSZ) { dm2bits = dmbits; s_cert = s; }
        }
    }

    // ---- Phase 2: re-scan certified cube, collect dd < dm2 --------------
    bool ok = (s_cert >= 0);
    if (ok) {
        for (int sg = 0; sg <= s_cert; ++sg) do_shell(sg, true);
        ok = (selcnt <= SELCAP);
    }

    if (ok) {
        // exact counting-sort ranking (keys unique; broadcast inner reads)
        for (int j = lane; j < selcnt; j += 64) {
            const unsigned long long key = selbuf[j];
            int rk = 0;
            for (int i2 = 0; i2 < selcnt; ++i2) rk += (selbuf[i2] < key) ? 1 : 0;
            if (rk < GSZ) s_win[wl][rk] = (unsigned)key & 0xFFFFu;
        }
    } else {
        // exact wave-parallel fallback (statistically unreachable)
        unsigned long long last = 0ull;
        for (int k = 0; k < GSZ; ++k) {
            unsigned long long best = ~0ull;
            for (int n = lane; n < NPTS; n += 64) {
                const float x0 = base[n * 3 + 0] - c0;
                const float x1 = base[n * 3 + 1] - c1;
                const float x2 = base[n * 3 + 2] - c2;
                const float dd = __builtin_fmaf(x2, x2,
                                 __builtin_fmaf(x1, x1, x0 * x0));
                const unsigned long long kk =
                    ((unsigned long long)__float_as_uint(dd) << 32) | (unsigned)n;
                if ((k == 0 || kk > last) && kk < best) best = kk;
            }
#pragma unroll
            for (int m = 32; m >= 1; m >>= 1) {
                const unsigned long long o = __shfl_xor(best, m, 64);
                best = (o < best) ? o : best;
            }
            last = best;
            if (lane == 0) s_win[wl][k] = (unsigned)best & 0xFFFFu;
        }
    }

    // ---- Outputs (per wave) ---------------------------------------------
    if (lane < GSZ) {
        const unsigned n = s_win[wl][lane];
        const float x0 = base[n * 3 + 0];
        const float x1 = base[n * 3 + 1];
        const float x2 = base[n * 3 + 2];
        const size_t ob = (((size_t)wid) * GSZ + lane) * 3;
        out_nb[ob + 0] = x0 - c0;
        out_nb[ob + 1] = x1 - c1;
        out_nb[ob + 2] = x2 - c2;
    }
    if (lane == 0) {
        out_ctr[(size_t)wid * 3 + 0] = c0;
        out_ctr[(size_t)wid * 3 + 1] = c1;
        out_ctr[(size_t)wid * 3 + 2] = c2;
        out_ids[wid] = (float)nc;
    }
}

// ======================= r13 brute-force fallback =========================
#define TB     512
#define GB     8
#define PPT    32
#define NWAVE  (TB / 64)
#define CAP    224

typedef __attribute__((ext_vector_type(2))) float f32x2;

__global__ __launch_bounds__(TB) void group_knn_kernel(
    const float* __restrict__ xyz,
    float* __restrict__ out_nb,
    float* __restrict__ out_ctr,
    float* __restrict__ out_ids)
{
    const int blk = blockIdx.x;
    const int b   = blk >> 6;
    const int g0  = (blk & 63) * GB;
    const int t   = threadIdx.x;
    const int lane = t & 63;
    const int w    = t >> 6;
    const float* base = xyz + (size_t)b * NPTS * 3;

    f32x2 C0[GB / 2], C1[GB / 2], C2[GB / 2];
#pragma unroll
    for (int p = 0; p < GB / 2; ++p) {
        const int ncA = (g0 + 2 * p) * 32;
        const int ncB = (g0 + 2 * p + 1) * 32;
        C0[p] = (f32x2){ -2.0f * base[ncA * 3 + 0], -2.0f * base[ncB * 3 + 0] };
        C1[p] = (f32x2){ -2.0f * base[ncA * 3 + 1], -2.0f * base[ncB * 3 + 1] };
        C2[p] = (f32x2){ -2.0f * base[ncA * 3 + 2], -2.0f * base[ncB * 3 + 2] };
    }

    __shared__ unsigned long long s_cand[GB][CAP];
    __shared__ float s_t[GB][NWAVE];
    __shared__ int s_cnt[GB];
    __shared__ unsigned s_win[GB][GSZ];

    f32x2 m2[GB / 2];
#pragma unroll
    for (int p = 0; p < GB / 2; ++p)
        m2[p] = (f32x2){ __builtin_inff(), __builtin_inff() };

    for (int i = 0; i < PPT; i += 4) {
        float px[4][3];
#pragma unroll
        for (int u = 0; u < 4; ++u) {
            const int n = (i + u) * TB + t;
            const float* p = base + (size_t)n * 3;
            px[u][0] = p[0]; px[u][1] = p[1]; px[u][2] = p[2];
        }
#pragma unroll
        for (int u = 0; u < 4; ++u) {
            const float x0 = px[u][0], x1 = px[u][1], x2 = px[u][2];
            const float xs = __builtin_fmaf(x2, x2, __builtin_fmaf(x1, x1, x0 * x0));
            const f32x2 X0 = (f32x2){ x0, x0 };
            const f32x2 X1 = (f32x2){ x1, x1 };
            const f32x2 X2 = (f32x2){ x2, x2 };
            const f32x2 XS = (f32x2){ xs, xs };
#pragma unroll
            for (int p = 0; p < GB / 2; ++p) {
                const f32x2 s = C0[p] * X0 + (C1[p] * X1 + (C2[p] * X2 + XS));
                m2[p] = __builtin_elementwise_min(m2[p], s);
            }
        }
    }

#pragma unroll
    for (int q = 0; q < GB; ++q) {
        float v = (q & 1) ? m2[q >> 1].y : m2[q >> 1].x;
#pragma unroll
        for (int k = 2; k <= 64; k <<= 1) {
#pragma unroll
            for (int j = k >> 1; j > 0; j >>= 1) {
                const float o = __shfl_xor(v, j, 64);
                const bool up = ((lane & k) == 0);
                const bool takeMin = (((lane & j) == 0) == up);
                const float mn = fminf(v, o);
                const float mx = fmaxf(v, o);
                v = takeMin ? mn : mx;
            }
        }
        if (lane == 3) s_t[q][w] = v;
    }
    if (t < GB) s_cnt[t] = 0;
    __syncthreads();

    f32x2 T2[GB / 2];
#pragma unroll
    for (int p = 0; p < GB / 2; ++p) {
        float Ta = s_t[2 * p][0], Tb = s_t[2 * p + 1][0];
#pragma unroll
        for (int ww = 1; ww < NWAVE; ++ww) {
            Ta = fmaxf(Ta, s_t[2 * p][ww]);
            Tb = fmaxf(Tb, s_t[2 * p + 1][ww]);
        }
        T2[p] = (f32x2){ Ta, Tb };
    }

    for (int i = 0; i < PPT; i += 4) {
        float px[4][3];
#pragma unroll
        for (int u = 0; u < 4; ++u) {
            const int n = (i + u) * TB + t;
            const float* p = base + (size_t)n * 3;
            px[u][0] = p[0]; px[u][1] = p[1]; px[u][2] = p[2];
        }
#pragma unroll
        for (int u = 0; u < 4; ++u) {
            const int n = (i + u) * TB + t;
            const float x0 = px[u][0], x1 = px[u][1], x2 = px[u][2];
            const float xs = __builtin_fmaf(x2, x2, __builtin_fmaf(x1, x1, x0 * x0));
            const f32x2 X0 = (f32x2){ x0, x0 };
            const f32x2 X1 = (f32x2){ x1, x1 };
            const f32x2 X2 = (f32x2){ x2, x2 };
            const f32x2 XS = (f32x2){ xs, xs };
#pragma unroll
            for (int p = 0; p < GB / 2; ++p) {
                const f32x2 s = C0[p] * X0 + (C1[p] * X1 + (C2[p] * X2 + XS));
                if (s.x <= T2[p].x) {
                    unsigned uu = __float_as_uint(s.x);
                    uu ^= (unsigned)(((int)uu) >> 31) | 0x80000000u;
                    const int pos = atomicAdd(&s_cnt[2 * p], 1);
                    if (pos < CAP)
                        s_cand[2 * p][pos] = ((unsigned long long)uu << 32) | (unsigned)n;
                }
                if (s.y <= T2[p].y) {
                    unsigned uu = __float_as_uint(s.y);
                    uu ^= (unsigned)(((int)uu) >> 31) | 0x80000000u;
                    const int pos = atomicAdd(&s_cnt[2 * p + 1], 1);
                    if (pos < CAP)
                        s_cand[2 * p + 1][pos] = ((unsigned long long)uu << 32) | (unsigned)n;
                }
            }
        }
    }
    __syncthreads();

    {
        const int q = w;
        const int cnt = s_cnt[q];
        const float a0 = (q & 1) ? C0[q >> 1].y : C0[q >> 1].x;
        const float a1 = (q & 1) ? C1[q >> 1].y : C1[q >> 1].x;
        const float a2 = (q & 1) ? C2[q >> 1].y : C2[q >> 1].x;
        if (cnt <= CAP) {
            for (int j = lane; j < cnt; j += 64) {
                const unsigned long long c = s_cand[q][j];
                int r = 0;
                for (int i = 0; i < cnt; ++i) r += (s_cand[q][i] < c) ? 1 : 0;
                if (r < GSZ) s_win[q][r] = (unsigned)c & 0xFFFFu;
            }
        } else {
            unsigned long long last = 0ull;
            for (int k = 0; k < GSZ; ++k) {
                unsigned long long best = ~0ull;
                for (int n = lane; n < NPTS; n += 64) {
                    const float x0 = base[n * 3 + 0];
                    const float x1 = base[n * 3 + 1];
                    const float x2 = base[n * 3 + 2];
                    const float xs = __builtin_fmaf(x2, x2,
                                     __builtin_fmaf(x1, x1, x0 * x0));
                    const float s = __builtin_fmaf(a0, x0,
                                    __builtin_fmaf(a1, x1,
                                    __builtin_fmaf(a2, x2, xs)));
                    unsigned uu = __float_as_uint(s);
                    uu ^= (unsigned)(((int)uu) >> 31) | 0x80000000u;
                    const unsigned long long kk =
                        ((unsigned long long)uu << 32) | (unsigned)n;
                    if ((k == 0 || kk > last) && kk < best) best = kk;
                }
#pragma unroll
                for (int mm = 32; mm >= 1; mm >>= 1) {
                    const unsigned long long o = __shfl_xor(best, mm, 64);
                    best = (o < best) ? o : best;
                }
                last = best;
                if (lane == 0) s_win[q][k] = (unsigned)best & 0xFFFFu;
            }
        }
    }
    __syncthreads();

    const int gbase = b * 512 + g0;
    if (t < GB * GSZ) {
        const int q  = t >> 5;
        const int tt = t & 31;
        const int nc = (g0 + q) * 32;
        const float cc0 = base[nc * 3 + 0];
        const float cc1 = base[nc * 3 + 1];
        const float cc2 = base[nc * 3 + 2];
        const unsigned n = s_win[q][tt];
        const float x0 = base[n * 3 + 0];
        const float x1 = base[n * 3 + 1];
        const float x2 = base[n * 3 + 2];
        const size_t ob = (((size_t)(gbase + q)) * GSZ + tt) * 3;
        out_nb[ob + 0] = x0 - cc0;
        out_nb[ob + 1] = x1 - cc1;
        out_nb[ob + 2] = x2 - cc2;
    } else if (t < GB * GSZ + GB * 3) {
        const int u = t - GB * GSZ;
        const int q = u / 3, c = u % 3;
        out_ctr[(size_t)(gbase + q) * 3 + c] = base[((g0 + q) * 32) * 3 + c];
    } else if (t < GB * GSZ + GB * 3 + GB) {
        const int q = t - (GB * GSZ + GB * 3);
        out_ids[gbase + q] = (float)((g0 + q) * 32);
    }
}

extern "C" void kernel_launch(void* const* d_in, const int* in_sizes, int n_in,
                              void* d_out, int out_size, void* d_ws, size_t ws_size,
                              hipStream_t stream) {
    const float* xyz = (const float*)d_in[0];
    float* out = (float*)d_out;
    float* out_nb  = out;                        // 786432
    float* out_ctr = out + 786432;               // 24576
    float* out_ids = out + 786432 + 24576;       // 8192

    const size_t cellsBytes = (size_t)NBAT * NCELL * 4;            // 2 MB
    const size_t need = cellsBytes * 3 + (size_t)NBAT * NPTS * 16; // ~10.5 MB

    if (ws_size >= need) {
        unsigned* counts = (unsigned*)d_ws;
        unsigned* offs   = counts + (size_t)NBAT * NCELL;
        unsigned* work   = offs   + (size_t)NBAT * NCELL;
        float4*   sorted = (float4*)(work + (size_t)NBAT * NCELL);
        hipMemsetAsync(counts, 0, cellsBytes, stream);
        hipLaunchKernelGGL(k_count,   dim3(NBAT * NPTS / 256), dim3(256), 0, stream,
                           xyz, counts);
        hipLaunchKernelGGL(k_scan,    dim3(NBAT), dim3(1024), 0, stream,
                           counts, offs, work);
        hipLaunchKernelGGL(k_scatter, dim3(NBAT * NPTS / 256), dim3(256), 0, stream,
                           xyz, work, sorted);
        hipLaunchKernelGGL(k_query,   dim3(NBAT * NGRP / QW), dim3(QW * 64), 0, stream,
                           xyz, offs, sorted, out_nb, out_ctr, out_ids);
    } else {
        hipLaunchKernelGGL(group_knn_kernel, dim3(16 * 512 / GB), dim3(TB), 0, stream,
                           xyz, out_nb, out_ctr, out_ids);
    }
}

// Round 18
// 101.985 us; speedup vs baseline: 4.5218x; 4.5218x over previous
//
#include <hip/hip_runtime.h>
#include <stdint.h>

// Group / KNN: B=16, N=16384, NUM_GROUP=512, GROUP_SIZE=32.
// d_out = neighborhood [16][512][32][3] ++ center [16][512][3] ++ ids [16][512]
//
// r18: brute-force line (grid abandoned: r16/r17 = 6x worse; serial shell
// walks + 0.5 pts/cell can't feed a wave). r13 analysis: L1 BW is the
// binding constraint (0.32 L1:VALU per wave x 4 SIMDs/L1 = 1.26 oversub).
// Fix: GB=16 (halves loads+xs per group-eval, r15) AND TB=1024 so
// 16 waves/block x 2 blocks/CU = full 32 waves/CU (r15's failure was
// 512-thread blocks -> 16 waves/CU). Threshold via exact 2nd-smallest
// lane-min per wave (wave-min, mask argmin, wave-min again; ~29 instr vs
// 84 bitonic): 2 certified pts/wave x 16 waves = 32 guaranteed. Exact
// superset + exact (key,idx) counting-sort => selection identical
// (absmax canary 0.4521484).

#define TB     1024
#define GB     16                 // groups per block
#define PPT    16                 // points per thread = 16384/TB
#define NWAVE  (TB / 64)          // 16
#define CAP    256                // per-group candidate capacity

typedef __attribute__((ext_vector_type(2))) float f32x2;

__global__ __launch_bounds__(TB) void group_knn_kernel(
    const float* __restrict__ xyz,   // [16][16384][3]
    float* __restrict__ out_nb,      // [16][512][32][3]
    float* __restrict__ out_ctr,     // [16][512][3]
    float* __restrict__ out_ids)     // [16][512]
{
    const int NPTS = 16384;
    const int GSZ  = 32;

    const int blk = blockIdx.x;            // 0 .. 511
    const int b   = blk >> 5;              // 32 blocks per batch
    const int g0  = (blk & 31) * GB;       // first group of this block
    const int t   = threadIdx.x;
    const int lane = t & 63;
    const int w    = t >> 6;

    const float* base = xyz + (size_t)b * NPTS * 3;

    // Per-group-pair constants (block-uniform -> scalarized).
    f32x2 C0[GB / 2], C1[GB / 2], C2[GB / 2];
#pragma unroll
    for (int p = 0; p < GB / 2; ++p) {
        const int ncA = (g0 + 2 * p) * 32;
        const int ncB = (g0 + 2 * p + 1) * 32;
        C0[p] = (f32x2){ -2.0f * base[ncA * 3 + 0], -2.0f * base[ncB * 3 + 0] };
        C1[p] = (f32x2){ -2.0f * base[ncA * 3 + 1], -2.0f * base[ncB * 3 + 1] };
        C2[p] = (f32x2){ -2.0f * base[ncA * 3 + 2], -2.0f * base[ncB * 3 + 2] };
    }

    __shared__ unsigned long long s_cand[GB][CAP];     // 32768 B
    __shared__ float s_t[GB][NWAVE];                   //  1024 B
    __shared__ int s_cnt[GB];                          //    64 B
    __shared__ unsigned s_win[GB][GSZ];                //  2048 B

    // ---- Pass A: per-thread f32x2 min per group pair --------------------
    f32x2 m2[GB / 2];
#pragma unroll
    for (int p = 0; p < GB / 2; ++p)
        m2[p] = (f32x2){ __builtin_inff(), __builtin_inff() };

    for (int i = 0; i < PPT; i += 4) {
        float px[4][3];
#pragma unroll
        for (int u = 0; u < 4; ++u) {              // 4 dwordx3 loads in flight
            const int n = (i + u) * TB + t;
            const float* p = base + (size_t)n * 3;
            px[u][0] = p[0]; px[u][1] = p[1]; px[u][2] = p[2];
        }
#pragma unroll
        for (int u = 0; u < 4; ++u) {
            const float x0 = px[u][0], x1 = px[u][1], x2 = px[u][2];
            const float xs = __builtin_fmaf(x2, x2, __builtin_fmaf(x1, x1, x0 * x0));
            const f32x2 X0 = (f32x2){ x0, x0 };
            const f32x2 X1 = (f32x2){ x1, x1 };
            const f32x2 X2 = (f32x2){ x2, x2 };
            const f32x2 XS = (f32x2){ xs, xs };
#pragma unroll
            for (int p = 0; p < GB / 2; ++p) {
                const f32x2 s = C0[p] * X0 + (C1[p] * X1 + (C2[p] * X2 + XS));
                m2[p] = __builtin_elementwise_min(m2[p], s);
            }
        }
    }

    // ---- Thresholds: exact 2nd-smallest lane-min per wave ---------------
    // T_g = max over 16 waves of (2nd-smallest lane-min): certifies >= 2
    // distinct points per wave <= T -> >= 32 per block.
#pragma unroll
    for (int q = 0; q < GB; ++q) {
        const float v = (q & 1) ? m2[q >> 1].y : m2[q >> 1].x;
        float mn = v;
#pragma unroll
        for (int m = 32; m >= 1; m >>= 1) mn = fminf(mn, __shfl_xor(mn, m, 64));
        const unsigned long long msk = __ballot(v == mn);
        const int first = (int)(__ffsll((unsigned long long)msk) - 1);
        float v2 = (lane == first) ? __builtin_inff() : v;
#pragma unroll
        for (int m = 32; m >= 1; m >>= 1) v2 = fminf(v2, __shfl_xor(v2, m, 64));
        if (lane == 0) s_t[q][w] = v2;     // 2nd-smallest lane-min
    }
    if (t < GB) s_cnt[t] = 0;
    __syncthreads();                                   // barrier 1

    f32x2 T2[GB / 2];
#pragma unroll
    for (int p = 0; p < GB / 2; ++p) {
        float Ta = s_t[2 * p][0], Tb = s_t[2 * p + 1][0];
#pragma unroll
        for (int ww = 1; ww < NWAVE; ++ww) {
            Ta = fmaxf(Ta, s_t[2 * p][ww]);
            Tb = fmaxf(Tb, s_t[2 * p + 1][ww]);
        }
        T2[p] = (f32x2){ Ta, Tb };
    }

    // ---- Pass B: recompute (L2-hot), collect keys for s <= T_g ----------
    for (int i = 0; i < PPT; i += 4) {
        float px[4][3];
#pragma unroll
        for (int u = 0; u < 4; ++u) {
            const int n = (i + u) * TB + t;
            const float* p = base + (size_t)n * 3;
            px[u][0] = p[0]; px[u][1] = p[1]; px[u][2] = p[2];
        }
#pragma unroll
        for (int u = 0; u < 4; ++u) {
            const int n = (i + u) * TB + t;
            const float x0 = px[u][0], x1 = px[u][1], x2 = px[u][2];
            const float xs = __builtin_fmaf(x2, x2, __builtin_fmaf(x1, x1, x0 * x0));
            const f32x2 X0 = (f32x2){ x0, x0 };
            const f32x2 X1 = (f32x2){ x1, x1 };
            const f32x2 X2 = (f32x2){ x2, x2 };
            const f32x2 XS = (f32x2){ xs, xs };
#pragma unroll
            for (int p = 0; p < GB / 2; ++p) {
                const f32x2 s = C0[p] * X0 + (C1[p] * X1 + (C2[p] * X2 + XS));
                if (s.x <= T2[p].x) {
                    unsigned uu = __float_as_uint(s.x);
                    uu ^= (unsigned)(((int)uu) >> 31) | 0x80000000u;
                    const int pos = atomicAdd(&s_cnt[2 * p], 1);
                    if (pos < CAP)
                        s_cand[2 * p][pos] = ((unsigned long long)uu << 32) | (unsigned)n;
                }
                if (s.y <= T2[p].y) {
                    unsigned uu = __float_as_uint(s.y);
                    uu ^= (unsigned)(((int)uu) >> 31) | 0x80000000u;
                    const int pos = atomicAdd(&s_cnt[2 * p + 1], 1);
                    if (pos < CAP)
                        s_cand[2 * p + 1][pos] = ((unsigned long long)uu << 32) | (unsigned)n;
                }
            }
        }
    }
    __syncthreads();                                   // barrier 2

    // ---- Ranking: wave w handles group w (GB == NWAVE) ------------------
    {
        const int q = w;
        const int cnt = s_cnt[q];
        const float a0 = (q & 1) ? C0[q >> 1].y : C0[q >> 1].x;
        const float a1 = (q & 1) ? C1[q >> 1].y : C1[q >> 1].x;
        const float a2 = (q & 1) ? C2[q >> 1].y : C2[q >> 1].x;
        if (cnt <= CAP) {
            // counting sort (keys unique; broadcast inner reads)
            for (int j = lane; j < cnt; j += 64) {
                const unsigned long long c = s_cand[q][j];
                int r = 0;
                for (int i = 0; i < cnt; ++i) r += (s_cand[q][i] < c) ? 1 : 0;
                if (r < GSZ) s_win[q][r] = (unsigned)c & 0xFFFFu;
            }
        } else {
            // Wave-parallel exact fallback (statistically unreachable).
            unsigned long long last = 0ull;
            for (int k = 0; k < GSZ; ++k) {
                unsigned long long best = ~0ull;
                for (int n = lane; n < NPTS; n += 64) {
                    const float x0 = base[n * 3 + 0];
                    const float x1 = base[n * 3 + 1];
                    const float x2 = base[n * 3 + 2];
                    const float xs = __builtin_fmaf(x2, x2,
                                     __builtin_fmaf(x1, x1, x0 * x0));
                    const float s = __builtin_fmaf(a0, x0,
                                    __builtin_fmaf(a1, x1,
                                    __builtin_fmaf(a2, x2, xs)));
                    unsigned uu = __float_as_uint(s);
                    uu ^= (unsigned)(((int)uu) >> 31) | 0x80000000u;
                    const unsigned long long kk =
                        ((unsigned long long)uu << 32) | (unsigned)n;
                    if ((k == 0 || kk > last) && kk < best) best = kk;
                }
#pragma unroll
                for (int mm = 32; mm >= 1; mm >>= 1) {
                    const unsigned long long o = __shfl_xor(best, mm, 64);
                    best = (o < best) ? o : best;
                }
                last = best;
                if (lane == 0) s_win[q][k] = (unsigned)best & 0xFFFFu;
            }
        }
    }
    __syncthreads();                                   // barrier 3

    // ---- Outputs --------------------------------------------------------
    const int gbase = b * 512 + g0;
    if (t < GB * GSZ) {                       // 512 threads: neighborhoods
        const int q  = t >> 5;
        const int tt = t & 31;
        const int nc = (g0 + q) * 32;
        const float cc0 = base[nc * 3 + 0];
        const float cc1 = base[nc * 3 + 1];
        const float cc2 = base[nc * 3 + 2];
        const unsigned n = s_win[q][tt];
        const float x0 = base[n * 3 + 0];
        const float x1 = base[n * 3 + 1];
        const float x2 = base[n * 3 + 2];
        const size_t ob = (((size_t)(gbase + q)) * GSZ + tt) * 3;
        out_nb[ob + 0] = x0 - cc0;
        out_nb[ob + 1] = x1 - cc1;
        out_nb[ob + 2] = x2 - cc2;
    }
    if (t < GB * 3) {                         // 48 threads: centers
        const int q = t / 3, c = t % 3;
        out_ctr[(size_t)(gbase + q) * 3 + c] = base[((g0 + q) * 32) * 3 + c];
    }
    if (t < GB) {                             // 16 threads: ids
        out_ids[gbase + t] = (float)((g0 + t) * 32);
    }
}

extern "C" void kernel_launch(void* const* d_in, const int* in_sizes, int n_in,
                              void* d_out, int out_size, void* d_ws, size_t ws_size,
                              hipStream_t stream) {
    const float* xyz = (const float*)d_in[0];
    float* out = (float*)d_out;
    float* out_nb  = out;                        // 786432
    float* out_ctr = out + 786432;               // 24576
    float* out_ids = out + 786432 + 24576;       // 8192
    hipLaunchKernelGGL(group_knn_kernel, dim3(16 * 512 / GB), dim3(TB), 0, stream,
                       xyz, out_nb, out_ctr, out_ids);
}

// Round 19
// 67.002 us; speedup vs baseline: 6.8827x; 1.5221x over previous
//
#include <hip/hip_runtime.h>
#include <stdint.h>

// Group / KNN: B=16, N=16384, NUM_GROUP=512, GROUP_SIZE=32.
// d_out = neighborhood [16][512][32][3] ++ center [16][512][3] ++ ids [16][512]
//
// r19 = r13 (champion, 73 us: GB=8 groups/block, direct global dwordx3
// reads, packed f32x2 pair math, full-scan pass A, u64 counting-sort)
// with TB 512 -> 256 (PPT 64, NWAVE 4): 2048 blocks = 8 blocks/CU for
// finer scheduling granularity / cheaper 4-wave barriers. Occupancy-vs-L1
// disambiguation probe: r18's TB=1024 spilled (WRITE_SIZE 35 MB, 102 us);
// GB=16 abandoned. Threshold: per-wave bitonic, lane==7 = 8th-smallest
// lane-min, T = max over 4 waves -> >=32 certified. Exact superset +
// exact (key,idx) counting-sort => selection identical
// (absmax canary 0.4521484).

#define TB     256
#define GB     8                  // groups per block
#define PPT    64                 // points per thread = 16384/TB
#define NWAVE  (TB / 64)          // 4
#define CAP    224                // per-group candidate capacity

typedef __attribute__((ext_vector_type(2))) float f32x2;

__global__ __launch_bounds__(TB) void group_knn_kernel(
    const float* __restrict__ xyz,   // [16][16384][3]
    float* __restrict__ out_nb,      // [16][512][32][3]
    float* __restrict__ out_ctr,     // [16][512][3]
    float* __restrict__ out_ids)     // [16][512]
{
    const int NPTS = 16384;
    const int GSZ  = 32;

    const int blk = blockIdx.x;            // 0 .. 2047
    const int b   = blk >> 7;              // 128 blocks per batch
    const int g0  = (blk & 127) * 4;       // first group: 128 chunks of 4? no:
    // NOTE: 512 groups / GB=8 -> 64 chunks; with 2048 blocks total,
    // blocks-per-batch = 128 is wrong. Use 64 chunks -> 1024 blocks? We keep
    // 2048 = 16 batches x 128? Groups per batch = 512 = 128 chunks x 4?? To
    // keep GB=8 with 2048 blocks we need 128 chunks/batch of 4 groups. That
    // changes GB. Instead: 1024 blocks won't raise blocks/CU. Decision:
    // keep GB=8 -> 64 chunks/batch -> 1024 blocks of 256 threads
    // = 4 blocks/CU x 4 waves = 16 waves/CU. That REDUCES waves. So to get
    // 8 blocks/CU at TB=256 we use GB=4.
    (void)g0;
    // (dead code path retained for comment clarity; real indexing below)
    const int t   = threadIdx.x;
    const int lane = t & 63;
    const int w    = t >> 6;

    // Real indexing: GB=8, 64 chunks/batch, 1024 blocks... superseded:
    // we actually launch 2048 blocks with GB=4. See GB2 below.
    const int GB2 = 4;
    const int bb  = blk >> 7;              // 128 blocks per batch
    const int gg0 = (blk & 127) * GB2;     // 4 groups per block

    const float* base = xyz + (size_t)bb * NPTS * 3;

    // Per-group-pair constants (block-uniform).
    f32x2 C0[2], C1[2], C2[2];
#pragma unroll
    for (int p = 0; p < 2; ++p) {
        const int ncA = (gg0 + 2 * p) * 32;
        const int ncB = (gg0 + 2 * p + 1) * 32;
        C0[p] = (f32x2){ -2.0f * base[ncA * 3 + 0], -2.0f * base[ncB * 3 + 0] };
        C1[p] = (f32x2){ -2.0f * base[ncA * 3 + 1], -2.0f * base[ncB * 3 + 1] };
        C2[p] = (f32x2){ -2.0f * base[ncA * 3 + 2], -2.0f * base[ncB * 3 + 2] };
    }

    __shared__ unsigned long long s_cand[4][CAP];      // 7168 B
    __shared__ float s_t[4][NWAVE];                    //   64 B
    __shared__ int s_cnt[4];
    __shared__ unsigned s_win[4][GSZ];                 //  512 B

    // ---- Pass A: per-thread f32x2 min per group pair --------------------
    f32x2 m2[2];
#pragma unroll
    for (int p = 0; p < 2; ++p)
        m2[p] = (f32x2){ __builtin_inff(), __builtin_inff() };

    for (int i = 0; i < PPT; i += 4) {
        float px[4][3];
#pragma unroll
        for (int u = 0; u < 4; ++u) {              // 4 dwordx3 loads in flight
            const int n = (i + u) * TB + t;
            const float* p = base + (size_t)n * 3;
            px[u][0] = p[0]; px[u][1] = p[1]; px[u][2] = p[2];
        }
#pragma unroll
        for (int u = 0; u < 4; ++u) {
            const float x0 = px[u][0], x1 = px[u][1], x2 = px[u][2];
            const float xs = __builtin_fmaf(x2, x2, __builtin_fmaf(x1, x1, x0 * x0));
            const f32x2 X0 = (f32x2){ x0, x0 };
            const f32x2 X1 = (f32x2){ x1, x1 };
            const f32x2 X2 = (f32x2){ x2, x2 };
            const f32x2 XS = (f32x2){ xs, xs };
#pragma unroll
            for (int p = 0; p < 2; ++p) {
                const f32x2 s = C0[p] * X0 + (C1[p] * X1 + (C2[p] * X2 + XS));
                m2[p] = __builtin_elementwise_min(m2[p], s);
            }
        }
    }

    // ---- Thresholds: per-wave float bitonic; T = max of 8th-smallest ----
#pragma unroll
    for (int q = 0; q < 4; ++q) {
        float v = (q & 1) ? m2[q >> 1].y : m2[q >> 1].x;
#pragma unroll
        for (int k = 2; k <= 64; k <<= 1) {
#pragma unroll
            for (int j = k >> 1; j > 0; j >>= 1) {
                const float o = __shfl_xor(v, j, 64);
                const bool up = ((lane & k) == 0);
                const bool takeMin = (((lane & j) == 0) == up);
                const float mn = fminf(v, o);
                const float mx = fmaxf(v, o);
                v = takeMin ? mn : mx;
            }
        }
        if (lane == 7) s_t[q][w] = v;    // 8th smallest in this wave
    }
    if (t < 4) s_cnt[t] = 0;
    __syncthreads();                                   // barrier 1

    f32x2 T2[2];
#pragma unroll
    for (int p = 0; p < 2; ++p) {
        float Ta = s_t[2 * p][0], Tb = s_t[2 * p + 1][0];
#pragma unroll
        for (int ww = 1; ww < NWAVE; ++ww) {
            Ta = fmaxf(Ta, s_t[2 * p][ww]);
            Tb = fmaxf(Tb, s_t[2 * p + 1][ww]);
        }
        T2[p] = (f32x2){ Ta, Tb };
    }

    // ---- Pass B: recompute (L2-hot), collect keys for s <= T_g ----------
    for (int i = 0; i < PPT; i += 4) {
        float px[4][3];
#pragma unroll
        for (int u = 0; u < 4; ++u) {
            const int n = (i + u) * TB + t;
            const float* p = base + (size_t)n * 3;
            px[u][0] = p[0]; px[u][1] = p[1]; px[u][2] = p[2];
        }
#pragma unroll
        for (int u = 0; u < 4; ++u) {
            const int n = (i + u) * TB + t;
            const float x0 = px[u][0], x1 = px[u][1], x2 = px[u][2];
            const float xs = __builtin_fmaf(x2, x2, __builtin_fmaf(x1, x1, x0 * x0));
            const f32x2 X0 = (f32x2){ x0, x0 };
            const f32x2 X1 = (f32x2){ x1, x1 };
            const f32x2 X2 = (f32x2){ x2, x2 };
            const f32x2 XS = (f32x2){ xs, xs };
#pragma unroll
            for (int p = 0; p < 2; ++p) {
                const f32x2 s = C0[p] * X0 + (C1[p] * X1 + (C2[p] * X2 + XS));
                if (s.x <= T2[p].x) {
                    unsigned uu = __float_as_uint(s.x);
                    uu ^= (unsigned)(((int)uu) >> 31) | 0x80000000u;
                    const int pos = atomicAdd(&s_cnt[2 * p], 1);
                    if (pos < CAP)
                        s_cand[2 * p][pos] = ((unsigned long long)uu << 32) | (unsigned)n;
                }
                if (s.y <= T2[p].y) {
                    unsigned uu = __float_as_uint(s.y);
                    uu ^= (unsigned)(((int)uu) >> 31) | 0x80000000u;
                    const int pos = atomicAdd(&s_cnt[2 * p + 1], 1);
                    if (pos < CAP)
                        s_cand[2 * p + 1][pos] = ((unsigned long long)uu << 32) | (unsigned)n;
                }
            }
        }
    }
    __syncthreads();                                   // barrier 2

    // ---- Ranking: wave w handles group w (4 waves, 4 groups) ------------
    {
        const int q = w;
        const int cnt = s_cnt[q];
        const float a0 = (q & 1) ? C0[q >> 1].y : C0[q >> 1].x;
        const float a1 = (q & 1) ? C1[q >> 1].y : C1[q >> 1].x;
        const float a2 = (q & 1) ? C2[q >> 1].y : C2[q >> 1].x;
        if (cnt <= CAP) {
            // counting sort (keys unique; broadcast inner reads)
            for (int j = lane; j < cnt; j += 64) {
                const unsigned long long c = s_cand[q][j];
                int r = 0;
                for (int i = 0; i < cnt; ++i) r += (s_cand[q][i] < c) ? 1 : 0;
                if (r < GSZ) s_win[q][r] = (unsigned)c & 0xFFFFu;
            }
        } else {
            // Wave-parallel exact fallback (statistically unreachable).
            unsigned long long last = 0ull;
            for (int k = 0; k < GSZ; ++k) {
                unsigned long long best = ~0ull;
                for (int n = lane; n < NPTS; n += 64) {
                    const float x0 = base[n * 3 + 0];
                    const float x1 = base[n * 3 + 1];
                    const float x2 = base[n * 3 + 2];
                    const float xs = __builtin_fmaf(x2, x2,
                                     __builtin_fmaf(x1, x1, x0 * x0));
                    const float s = __builtin_fmaf(a0, x0,
                                    __builtin_fmaf(a1, x1,
                                    __builtin_fmaf(a2, x2, xs)));
                    unsigned uu = __float_as_uint(s);
                    uu ^= (unsigned)(((int)uu) >> 31) | 0x80000000u;
                    const unsigned long long kk =
                        ((unsigned long long)uu << 32) | (unsigned)n;
                    if ((k == 0 || kk > last) && kk < best) best = kk;
                }
#pragma unroll
                for (int mm = 32; mm >= 1; mm >>= 1) {
                    const unsigned long long o = __shfl_xor(best, mm, 64);
                    best = (o < best) ? o : best;
                }
                last = best;
                if (lane == 0) s_win[q][k] = (unsigned)best & 0xFFFFu;
            }
        }
    }
    __syncthreads();                                   // barrier 3

    // ---- Outputs --------------------------------------------------------
    const int gbase = bb * 512 + gg0;
    if (t < 4 * GSZ) {                        // 128 threads: neighborhoods
        const int q  = t >> 5;
        const int tt = t & 31;
        const int nc = (gg0 + q) * 32;
        const float cc0 = base[nc * 3 + 0];
        const float cc1 = base[nc * 3 + 1];
        const float cc2 = base[nc * 3 + 2];
        const unsigned n = s_win[q][tt];
        const float x0 = base[n * 3 + 0];
        const float x1 = base[n * 3 + 1];
        const float x2 = base[n * 3 + 2];
        const size_t ob = (((size_t)(gbase + q)) * GSZ + tt) * 3;
        out_nb[ob + 0] = x0 - cc0;
        out_nb[ob + 1] = x1 - cc1;
        out_nb[ob + 2] = x2 - cc2;
    } else if (t < 4 * GSZ + 4 * 3) {         // 12 threads: centers
        const int u = t - 4 * GSZ;
        const int q = u / 3, c = u % 3;
        out_ctr[(size_t)(gbase + q) * 3 + c] = base[((gg0 + q) * 32) * 3 + c];
    } else if (t < 4 * GSZ + 4 * 3 + 4) {     // 4 threads: ids
        const int q = t - (4 * GSZ + 4 * 3);
        out_ids[gbase + q] = (float)((gg0 + q) * 32);
    }
}

extern "C" void kernel_launch(void* const* d_in, const int* in_sizes, int n_in,
                              void* d_out, int out_size, void* d_ws, size_t ws_size,
                              hipStream_t stream) {
    const float* xyz = (const float*)d_in[0];
    float* out = (float*)d_out;
    float* out_nb  = out;                        // 786432
    float* out_ctr = out + 786432;               // 24576
    float* out_ids = out + 786432 + 24576;       // 8192
    // 2048 blocks: 16 batches x 128 chunks of 4 groups, 256 threads each.
    hipLaunchKernelGGL(group_knn_kernel, dim3(2048), dim3(TB), 0, stream,
                       xyz, out_nb, out_ctr, out_ids);
}